// Round 1
// baseline (59.590 us; speedup 1.0000x reference)
//
#include <hip/hip_runtime.h>

namespace {

constexpr int Nn = 256;
constexpr int Bn = 64;
constexpr int SEG = 16;
constexpr int NSEG = Nn / SEG;   // 16

// Gaussian taps, sigma = 5*0.15+0.35 = 1.1
constexpr float KW0 = 0.07076638f;
constexpr float KW1 = 0.24446039f;
constexpr float KW2 = 0.36954646f;

constexpr float DEF_OFF   = 1.00784313725490196f;   // 1 + 2/255
constexpr float SCALE     = 0.01568627450980392f;   // 4/255
constexpr float INV_SCALE = 63.75f;                 // 255/4
constexpr float PW        = 0.0078125f;             // 2/256

__device__ __forceinline__ int reflN(int i) {
    if (i < 0) i = -i;
    if (i >= Nn) i = 2 * (Nn - 1) - i;
    return i;
}

__device__ __forceinline__ float seqf(int t) {
    return (float)(2 * t - (Nn - 1)) * (1.0f / (float)(Nn - 1));
}

// ---------------- Kernel 1: channel 0 -> gx (row-wise scan) ----------------
__global__ __launch_bounds__(256) void kx_kernel(const float* __restrict__ prim,
                                                 float* __restrict__ gx_out) {
    const int j = threadIdx.x;       // column
    const int i = blockIdx.x;        // row
    const int b = blockIdx.y;

    __shared__ float buf[Nn];
    __shared__ float srow[Nn];
    __shared__ float wsum[4];

    const float* base = prim + ((size_t)(b * 2 + 0) * Nn) * Nn;

    // vertical 5-tap (reflect rows)
    float v = 0.0f;
    v += KW0 * base[reflN(i - 2) * Nn + j];
    v += KW1 * base[reflN(i - 1) * Nn + j];
    v += KW2 * base[i * Nn + j];
    v += KW1 * base[reflN(i + 1) * Nn + j];
    v += KW0 * base[reflN(i + 2) * Nn + j];
    buf[j] = v;
    __syncthreads();

    // horizontal 5-tap (reflect cols)
    float h = KW0 * buf[reflN(j - 2)] + KW1 * buf[reflN(j - 1)] + KW2 * buf[j]
            + KW1 * buf[reflN(j + 1)] + KW0 * buf[reflN(j + 2)];
    float s = h + seqf(j) + DEF_OFF;
    srow[j] = s;
    __syncthreads();

    float sprev = (j > 0) ? srow[j - 1] : 0.0f;
    float accu = fmaxf((s - sprev) * INV_SCALE, 0.0f);

    // block-wide inclusive scan (wave shuffle + cross-wave LDS)
    const int lane = j & 63;
    const int wave = j >> 6;
    float val = accu;
    #pragma unroll
    for (int off = 1; off < 64; off <<= 1) {
        float u = __shfl_up(val, off, 64);
        if (lane >= off) val += u;
    }
    if (lane == 63) wsum[wave] = val;
    __syncthreads();
    float add = 0.0f;
    for (int w = 0; w < wave; ++w) add += wsum[w];
    val += add;

    float samp = val * SCALE - DEF_OFF;
    float sq = seqf(j);
    float p = fminf(fmaxf(samp - sq, -PW), PW);
    float g = fminf(fmaxf(p + sq, -1.0f), 1.0f);
    gx_out[((size_t)b * Nn + i) * Nn + j] = g;
}

// ------------- Kernels 2/4: channel 1, segmented column scan ---------------
// PHASE 0: per-segment partial sums of relu'd column diffs.
// PHASE 1: finish scan with carry, compute gy, fused bilinear gather + store.
template <int PHASE>
__global__ __launch_bounds__(256) void ky_kernel(const float* __restrict__ prim,
                                                 float* __restrict__ partial,
                                                 const float* __restrict__ gx_buf,
                                                 const float* __restrict__ image,
                                                 float* __restrict__ outp) {
    const int j   = threadIdx.x;
    const int seg = blockIdx.x;
    const int b   = blockIdx.y;
    const int i0  = seg * SEG;
    const int base_r = i0 - 3;   // first hrow slot

    __shared__ float hr[SEG + 5][Nn];   // 21 horizontally-convolved rows
    __shared__ float raw[Nn];

    const float* src = prim + ((size_t)(b * 2 + 1) * Nn) * Nn;

    for (int t = 0; t < SEG + 5; ++t) {
        int rr = reflN(base_r + t);
        float x = src[rr * Nn + j];
        raw[j] = x;
        __syncthreads();
        float h = KW0 * raw[reflN(j - 2)] + KW1 * raw[reflN(j - 1)] + KW2 * raw[j]
                + KW1 * raw[reflN(j + 1)] + KW0 * raw[reflN(j + 2)];
        hr[t][j] = h;
        __syncthreads();
    }

    auto conv_s = [&](int i) -> float {
        int t = i - base_r;   // slot of center row
        float v = KW0 * hr[t - 2][j] + KW1 * hr[t - 1][j] + KW2 * hr[t][j]
                + KW1 * hr[t + 1][j] + KW0 * hr[t + 2][j];
        return v + seqf(i) + DEF_OFF;
    };

    float prev = (i0 == 0) ? 0.0f : conv_s(i0 - 1);

    if constexpr (PHASE == 0) {
        float sum = 0.0f;
        for (int i = i0; i < i0 + SEG; ++i) {
            float s = conv_s(i);
            sum += fmaxf((s - prev) * INV_SCALE, 0.0f);
            prev = s;
        }
        partial[((size_t)b * NSEG + seg) * Nn + j] = sum;
    } else {
        float cum = partial[((size_t)b * NSEG + seg) * Nn + j];   // exclusive carry
        for (int i = i0; i < i0 + SEG; ++i) {
            float s = conv_s(i);
            cum += fmaxf((s - prev) * INV_SCALE, 0.0f);
            prev = s;

            float samp = cum * SCALE - DEF_OFF;
            float sq = seqf(i);
            float p  = fminf(fmaxf(samp - sq, -PW), PW);
            float gy = fminf(fmaxf(p + sq, -1.0f), 1.0f);
            float gx = gx_buf[((size_t)b * Nn + i) * Nn + j];

            float ix = (gx + 1.0f) * 0.5f * (float)(Nn - 1);
            float iy = (gy + 1.0f) * 0.5f * (float)(Nn - 1);
            float x0f = floorf(ix), y0f = floorf(iy);
            int x0 = (int)x0f, y0 = (int)y0f;
            float wx1 = ix - x0f, wy1 = iy - y0f;
            float wx0 = 1.0f - wx1, wy0 = 1.0f - wy1;
            int x1 = x0 + 1, y1 = y0 + 1;

            bool vx0 = (x0 >= 0) && (x0 <= Nn - 1);
            bool vx1 = (x1 >= 0) && (x1 <= Nn - 1);
            bool vy0 = (y0 >= 0) && (y0 <= Nn - 1);
            bool vy1 = (y1 >= 0) && (y1 <= Nn - 1);
            int x0c = min(max(x0, 0), Nn - 1), x1c = min(max(x1, 0), Nn - 1);
            int y0c = min(max(y0, 0), Nn - 1), y1c = min(max(y1, 0), Nn - 1);

            float w00 = (vx0 && vy0) ? wx0 * wy0 : 0.0f;
            float w10 = (vx1 && vy0) ? wx1 * wy0 : 0.0f;
            float w01 = (vx0 && vy1) ? wx0 * wy1 : 0.0f;
            float w11 = (vx1 && vy1) ? wx1 * wy1 : 0.0f;

            #pragma unroll
            for (int c = 0; c < 3; ++c) {
                const float* img = image + (((size_t)b * 3 + c) * Nn) * Nn;
                float vo = w00 * img[y0c * Nn + x0c] + w10 * img[y0c * Nn + x1c]
                         + w01 * img[y1c * Nn + x0c] + w11 * img[y1c * Nn + x1c];
                outp[(((size_t)b * 3 + c) * Nn + i) * Nn + j] = vo;
            }
        }
    }
}

// ------------- Kernel 3: exclusive carry scan over segments ---------------
__global__ __launch_bounds__(256) void kb_kernel(float* __restrict__ partial) {
    const int j = threadIdx.x;
    const int b = blockIdx.x;
    float run = 0.0f;
    for (int seg = 0; seg < NSEG; ++seg) {
        size_t idx = ((size_t)b * NSEG + seg) * Nn + j;
        float p = partial[idx];
        partial[idx] = run;
        run += p;
    }
}

}  // namespace

extern "C" void kernel_launch(void* const* d_in, const int* in_sizes, int n_in,
                              void* d_out, int out_size, void* d_ws, size_t ws_size,
                              hipStream_t stream) {
    const float* image = (const float*)d_in[0];   // (B,3,N,N) f32
    const float* prim  = (const float*)d_in[1];   // (B,2,N,N) f32
    float* outp = (float*)d_out;                  // (B,3,N,N) f32

    float* gx_buf  = (float*)d_ws;                          // B*N*N floats (16MB)
    float* partial = gx_buf + (size_t)Bn * Nn * Nn;         // B*NSEG*N floats (1MB)

    kx_kernel<<<dim3(Nn, Bn), 256, 0, stream>>>(prim, gx_buf);
    ky_kernel<0><<<dim3(NSEG, Bn), 256, 0, stream>>>(prim, partial, nullptr, nullptr, nullptr);
    kb_kernel<<<Bn, 256, 0, stream>>>(partial);
    ky_kernel<1><<<dim3(NSEG, Bn), 256, 0, stream>>>(prim, partial, gx_buf, image, outp);
}

// Round 2
// 52.552 us; speedup vs baseline: 1.1339x; 1.1339x over previous
//
#include <hip/hip_runtime.h>

namespace {

constexpr int Nn = 256;
constexpr int Bn = 64;
constexpr int SEG = 8;
constexpr int NSEG = Nn / SEG;   // 32

// Gaussian taps, sigma = 5*0.15+0.35 = 1.1
constexpr float KW0 = 0.07076638f;
constexpr float KW1 = 0.24446039f;
constexpr float KW2 = 0.36954646f;

constexpr float DEF_OFF   = 1.00784313725490196f;   // 1 + 2/255
constexpr float SCALE     = 0.01568627450980392f;   // 4/255
constexpr float INV_SCALE = 63.75f;                 // 255/4
constexpr float PW        = 0.0078125f;             // 2/256

__device__ __forceinline__ int reflN(int i) {
    if (i < 0) i = -i;
    if (i >= Nn) i = 2 * (Nn - 1) - i;
    return i;
}

__device__ __forceinline__ float seqf(int t) {
    return (float)(2 * t - (Nn - 1)) * (1.0f / (float)(Nn - 1));
}

// ---- Kernel 1: conv both channels for one row; x-scan -> gx; store s_y ----
__global__ __launch_bounds__(256) void k1_kernel(const float* __restrict__ prim,
                                                 float* __restrict__ gx_out,
                                                 float* __restrict__ sy_out) {
    const int j = threadIdx.x;
    // XCD-locality swizzle of the row index (256 rows, 8 XCDs -> 32-row chunks)
    const int bx = blockIdx.x;
    const int i = (bx & 7) * 32 + (bx >> 3);
    const int b = blockIdx.y;

    __shared__ float buf0[Nn];
    __shared__ float buf1[Nn];
    __shared__ float srow[Nn];
    __shared__ float wsum[4];

    const float* c0 = prim + (size_t)(b * 2) * Nn * Nn;
    const float* c1 = c0 + (size_t)Nn * Nn;

    const int rm2 = reflN(i - 2) * Nn, rm1 = reflN(i - 1) * Nn, r0 = i * Nn,
              rp1 = reflN(i + 1) * Nn, rp2 = reflN(i + 2) * Nn;

    float v0 = KW0 * c0[rm2 + j] + KW1 * c0[rm1 + j] + KW2 * c0[r0 + j]
             + KW1 * c0[rp1 + j] + KW0 * c0[rp2 + j];
    float v1 = KW0 * c1[rm2 + j] + KW1 * c1[rm1 + j] + KW2 * c1[r0 + j]
             + KW1 * c1[rp1 + j] + KW0 * c1[rp2 + j];
    buf0[j] = v0;
    buf1[j] = v1;
    __syncthreads();

    const int jm2 = reflN(j - 2), jm1 = reflN(j - 1), jp1 = reflN(j + 1), jp2 = reflN(j + 2);
    float h0 = KW0 * buf0[jm2] + KW1 * buf0[jm1] + KW2 * buf0[j]
             + KW1 * buf0[jp1] + KW0 * buf0[jp2];
    float h1 = KW0 * buf1[jm2] + KW1 * buf1[jm1] + KW2 * buf1[j]
             + KW1 * buf1[jp1] + KW0 * buf1[jp2];

    // s_y (full, including identity + offset) -> ws
    sy_out[((size_t)b * Nn + i) * Nn + j] = h1 + seqf(i) + DEF_OFF;

    // x-channel: row scan
    float s = h0 + seqf(j) + DEF_OFF;
    srow[j] = s;
    __syncthreads();

    float sprev = (j > 0) ? srow[j - 1] : 0.0f;
    float accu = fmaxf((s - sprev) * INV_SCALE, 0.0f);

    const int lane = j & 63;
    const int wave = j >> 6;
    float val = accu;
    #pragma unroll
    for (int off = 1; off < 64; off <<= 1) {
        float u = __shfl_up(val, off, 64);
        if (lane >= off) val += u;
    }
    if (lane == 63) wsum[wave] = val;
    __syncthreads();
    float add = 0.0f;
    for (int w = 0; w < wave; ++w) add += wsum[w];
    val += add;

    float samp = val * SCALE - DEF_OFF;
    float sq = seqf(j);
    float p = fminf(fmaxf(samp - sq, -PW), PW);
    float g = fminf(fmaxf(p + sq, -1.0f), 1.0f);
    gx_out[((size_t)b * Nn + i) * Nn + j] = g;
}

// ---- Kernel 2: per-segment partial sums of relu'd column diffs (no LDS) ----
__global__ __launch_bounds__(256) void k2_kernel(const float* __restrict__ sy,
                                                 float* __restrict__ partial) {
    const int j = threadIdx.x;
    const int seg = blockIdx.x;
    const int b = blockIdx.y;
    const int i0 = seg * SEG;
    const float* sb = sy + (size_t)b * Nn * Nn;

    float prev = (i0 == 0) ? 0.0f : sb[(i0 - 1) * Nn + j];
    float sum = 0.0f;
    #pragma unroll
    for (int k = 0; k < SEG; ++k) {
        float sv = sb[(i0 + k) * Nn + j];
        sum += fmaxf((sv - prev) * INV_SCALE, 0.0f);
        prev = sv;
    }
    partial[((size_t)b * NSEG + seg) * Nn + j] = sum;
}

// ---- Kernel 3: carry + finish column scan + fused bilinear gather ----------
__global__ __launch_bounds__(256) void k3_kernel(const float* __restrict__ sy,
                                                 const float* __restrict__ partial,
                                                 const float* __restrict__ gx_buf,
                                                 const float* __restrict__ image,
                                                 float* __restrict__ outp) {
    const int j = threadIdx.x;
    const int seg = blockIdx.x;
    const int b = blockIdx.y;
    const int i0 = seg * SEG;
    const float* sb = sy + (size_t)b * Nn * Nn;

    // exclusive carry: masked unrolled loads of all 31 partials (independent,
    // L2-resident) — avoids a separate serial scan kernel
    const float* pb = partial + (size_t)b * NSEG * Nn + j;
    float carry = 0.0f;
    #pragma unroll
    for (int k = 0; k < NSEG - 1; ++k) {
        float p = pb[(size_t)k * Nn];
        carry += (k < seg) ? p : 0.0f;
    }

    float prev = (i0 == 0) ? 0.0f : sb[(i0 - 1) * Nn + j];
    float sv[SEG], gxv[SEG];
    #pragma unroll
    for (int k = 0; k < SEG; ++k) sv[k] = sb[(i0 + k) * Nn + j];
    #pragma unroll
    for (int k = 0; k < SEG; ++k) gxv[k] = gx_buf[((size_t)b * Nn + i0 + k) * Nn + j];

    float cum = carry;
    #pragma unroll
    for (int k = 0; k < SEG; ++k) {
        const int i = i0 + k;
        cum += fmaxf((sv[k] - prev) * INV_SCALE, 0.0f);
        prev = sv[k];

        float samp = cum * SCALE - DEF_OFF;
        float sq = seqf(i);
        float p  = fminf(fmaxf(samp - sq, -PW), PW);
        float gy = fminf(fmaxf(p + sq, -1.0f), 1.0f);
        float gx = gxv[k];

        float ix = (gx + 1.0f) * 0.5f * (float)(Nn - 1);
        float iy = (gy + 1.0f) * 0.5f * (float)(Nn - 1);
        float x0f = floorf(ix), y0f = floorf(iy);
        int x0 = (int)x0f, y0 = (int)y0f;
        float wx1 = ix - x0f, wy1 = iy - y0f;
        float wx0 = 1.0f - wx1, wy0 = 1.0f - wy1;
        int x1 = x0 + 1, y1 = y0 + 1;

        bool vx0 = (x0 >= 0) && (x0 <= Nn - 1);
        bool vx1 = (x1 >= 0) && (x1 <= Nn - 1);
        bool vy0 = (y0 >= 0) && (y0 <= Nn - 1);
        bool vy1 = (y1 >= 0) && (y1 <= Nn - 1);
        int x0c = min(max(x0, 0), Nn - 1), x1c = min(max(x1, 0), Nn - 1);
        int y0c = min(max(y0, 0), Nn - 1), y1c = min(max(y1, 0), Nn - 1);

        float w00 = (vx0 && vy0) ? wx0 * wy0 : 0.0f;
        float w10 = (vx1 && vy0) ? wx1 * wy0 : 0.0f;
        float w01 = (vx0 && vy1) ? wx0 * wy1 : 0.0f;
        float w11 = (vx1 && vy1) ? wx1 * wy1 : 0.0f;

        #pragma unroll
        for (int c = 0; c < 3; ++c) {
            const float* img = image + (((size_t)b * 3 + c) * Nn) * Nn;
            float vo = w00 * img[y0c * Nn + x0c] + w10 * img[y0c * Nn + x1c]
                     + w01 * img[y1c * Nn + x0c] + w11 * img[y1c * Nn + x1c];
            outp[(((size_t)b * 3 + c) * Nn + i) * Nn + j] = vo;
        }
    }
}

}  // namespace

extern "C" void kernel_launch(void* const* d_in, const int* in_sizes, int n_in,
                              void* d_out, int out_size, void* d_ws, size_t ws_size,
                              hipStream_t stream) {
    const float* image = (const float*)d_in[0];   // (B,3,N,N) f32
    const float* prim  = (const float*)d_in[1];   // (B,2,N,N) f32
    float* outp = (float*)d_out;                  // (B,3,N,N) f32

    float* gx_buf  = (float*)d_ws;                          // B*N*N floats (16MB)
    float* sy_buf  = gx_buf + (size_t)Bn * Nn * Nn;         // B*N*N floats (16MB)
    float* partial = sy_buf + (size_t)Bn * Nn * Nn;         // B*NSEG*N floats (2MB)

    k1_kernel<<<dim3(Nn, Bn), 256, 0, stream>>>(prim, gx_buf, sy_buf);
    k2_kernel<<<dim3(NSEG, Bn), 256, 0, stream>>>(sy_buf, partial);
    k3_kernel<<<dim3(NSEG, Bn), 256, 0, stream>>>(sy_buf, partial, gx_buf, image, outp);
}

// Round 3
// 42.649 us; speedup vs baseline: 1.3972x; 1.2322x over previous
//
#include <hip/hip_runtime.h>

namespace {

constexpr int Nn = 256;
constexpr int Bn = 64;
constexpr int SEG = 8;
constexpr int NSEG = Nn / SEG;   // 32

// Gaussian taps, sigma = 5*0.15+0.35 = 1.1
constexpr float KW0 = 0.07076638f;
constexpr float KW1 = 0.24446039f;
constexpr float KW2 = 0.36954646f;

constexpr float DEF_OFF   = 1.00784313725490196f;   // 1 + 2/255
constexpr float SCALE     = 0.01568627450980392f;   // 4/255
constexpr float INV_SCALE = 63.75f;                 // 255/4
constexpr float TWO255    = 0.00784313725490196f;   // 2/255 = seq step
constexpr float PW        = 0.0078125f;             // 2/256

__device__ __forceinline__ int reflN(int i) {
    if (i < 0) i = -i;
    if (i >= Nn) i = 2 * (Nn - 1) - i;
    return i;
}

__device__ __forceinline__ float seqf(int t) {
    return (float)(2 * t - (Nn - 1)) * (1.0f / (float)(Nn - 1));
}

// XCD-bijective swizzle: 2048 blocks, 8 XCDs -> each XCD gets a contiguous
// 256-block chunk (8 consecutive batches, all segs) for L2 locality.
__device__ __forceinline__ void segb(int lin, int& seg, int& b) {
    int wg = (lin & 7) * 256 + (lin >> 3);
    seg = wg & (NSEG - 1);
    b = wg >> 5;
}

// ---- Kernel A: conv both channels for an 8-row segment ---------------------
// outputs: gx (row-scanned+clipped), accu (relu'd column diffs), partial sums
__global__ __launch_bounds__(256) void kA_kernel(const float* __restrict__ prim,
                                                 float* __restrict__ gx_out,
                                                 float* __restrict__ accu_out,
                                                 float* __restrict__ partial) {
    const int j = threadIdx.x;
    int seg, b;
    segb(blockIdx.x, seg, b);
    const int i0 = seg * SEG;

    const float* c0 = prim + (size_t)b * 2 * Nn * Nn;
    const float* c1 = c0 + (size_t)Nn * Nn;

    // vertical 5-tap conv via rolling registers (all loads coalesced, independent)
    float a0[12], a1[13];
    #pragma unroll
    for (int t = 0; t < 12; ++t) a0[t] = c0[reflN(i0 - 2 + t) * Nn + j];
    #pragma unroll
    for (int t = 0; t < 13; ++t) a1[t] = c1[reflN(i0 - 3 + t) * Nn + j];

    __shared__ float vb[17][Nn];   // 8 ch0 rows + 9 ch1 rows, v-convolved
    __shared__ float wsum[SEG][4];

    #pragma unroll
    for (int r = 0; r < 8; ++r)
        vb[r][j] = KW0 * (a0[r] + a0[r + 4]) + KW1 * (a0[r + 1] + a0[r + 3]) + KW2 * a0[r + 2];
    #pragma unroll
    for (int r = 0; r < 9; ++r)
        vb[8 + r][j] = KW0 * (a1[r] + a1[r + 4]) + KW1 * (a1[r + 1] + a1[r + 3]) + KW2 * a1[r + 2];
    __syncthreads();

    const int jm3 = reflN(j - 3), jm2 = reflN(j - 2), jm1 = reflN(j - 1),
              jp1 = reflN(j + 1), jp2 = reflN(j + 2);
    const int lane = j & 63;
    const int wave = j >> 6;

    // ch0: h-conv, unified diff (s(j)-s(j-1) = h(j)-h(j-1)+2/255; s(0)=h(0)+2/255),
    // then per-row 256-wide scan
    float val[SEG];
    #pragma unroll
    for (int r = 0; r < 8; ++r) {
        const float* v = vb[r];
        float h  = KW0 * (v[jm2] + v[jp2]) + KW1 * (v[jm1] + v[jp1]) + KW2 * v[j];
        float hm = KW0 * (v[jm3] + v[jp1]) + KW1 * (v[jm2] + v[j])   + KW2 * v[jm1];
        if (j == 0) hm = 0.0f;
        float accu = fmaxf((h - hm + TWO255) * INV_SCALE, 0.0f);
        float s = accu;
        #pragma unroll
        for (int off = 1; off < 64; off <<= 1) {
            float u = __shfl_up(s, off, 64);
            if (lane >= off) s += u;
        }
        val[r] = s;
        if (lane == 63) wsum[r][wave] = s;
    }
    __syncthreads();

    const float sq_j = seqf(j);
    #pragma unroll
    for (int r = 0; r < 8; ++r) {
        float add = 0.0f;
        for (int w = 0; w < wave; ++w) add += wsum[r][w];
        float samp = (val[r] + add) * SCALE - DEF_OFF;
        float p = fminf(fmaxf(samp - sq_j, -PW), PW);
        float g = fminf(fmaxf(p + sq_j, -1.0f), 1.0f);
        gx_out[((size_t)b * Nn + i0 + r) * Nn + j] = g;
    }

    // ch1: h-conv for rows i0-1..i0+7, column diffs (along i, same j — register-local)
    float h1[9];
    #pragma unroll
    for (int r = 0; r < 9; ++r) {
        const float* v = vb[8 + r];
        h1[r] = KW0 * (v[jm2] + v[jp2]) + KW1 * (v[jm1] + v[jp1]) + KW2 * v[j];
    }
    float psum = 0.0f;
    #pragma unroll
    for (int rr = 0; rr < 8; ++rr) {
        float hm = (rr == 0 && seg == 0) ? 0.0f : h1[rr];
        float acc = fmaxf((h1[rr + 1] - hm + TWO255) * INV_SCALE, 0.0f);
        accu_out[((size_t)b * Nn + i0 + rr) * Nn + j] = acc;
        psum += acc;
    }
    partial[((size_t)b * NSEG + seg) * Nn + j] = psum;
}

// ---- Kernel 3: carry + column scan + LDS-tiled bilinear gather -------------
__global__ __launch_bounds__(256) void k3_kernel(const float* __restrict__ accu,
                                                 const float* __restrict__ partial,
                                                 const float* __restrict__ gx_buf,
                                                 const float* __restrict__ image,
                                                 float* __restrict__ outp) {
    const int j = threadIdx.x;
    int seg, b;
    segb(blockIdx.x, seg, b);
    const int i0 = seg * SEG;

    // exclusive carry over segment partials (independent, L2-resident loads)
    const float* pb = partial + (size_t)b * NSEG * Nn + j;
    float carry = 0.0f;
    #pragma unroll
    for (int k = 0; k < NSEG - 1; ++k) {
        float p = pb[(size_t)k * Nn];
        carry += (k < seg) ? p : 0.0f;
    }

    float av[SEG], gxv[SEG];
    #pragma unroll
    for (int k = 0; k < SEG; ++k) av[k] = accu[((size_t)b * Nn + i0 + k) * Nn + j];
    #pragma unroll
    for (int k = 0; k < SEG; ++k) gxv[k] = gx_buf[((size_t)b * Nn + i0 + k) * Nn + j];

    // phase A: finish column cumsum, compute sample coords + weights.
    // ix = j ± 127.5*PW (<1), iy = i ± (<1)  =>  corners lie in rows [i0-1, i0+8],
    // cols {j-1, j, j+1} — the 3x3 neighborhood. Stage rows in LDS, no gather.
    float wxs[SEG], wys[SEG];
    int x0s[SEG], y0s[SEG];
    float cum = carry;
    #pragma unroll
    for (int k = 0; k < SEG; ++k) {
        const int i = i0 + k;
        cum += av[k];
        float samp = cum * SCALE - DEF_OFF;
        float sq = seqf(i);
        float p  = fminf(fmaxf(samp - sq, -PW), PW);
        float gy = fminf(fmaxf(p + sq, -1.0f), 1.0f);
        float ix = (gxv[k] + 1.0f) * 127.5f;
        float iy = (gy + 1.0f) * 127.5f;
        float xf = floorf(ix), yf = floorf(iy);
        wxs[k] = ix - xf; wys[k] = iy - yf;
        x0s[k] = (int)xf; y0s[k] = (int)yf;
    }

    __shared__ float tile[10 * Nn];
    for (int c = 0; c < 3; ++c) {
        if (c) __syncthreads();
        const float* img = image + (size_t)(b * 3 + c) * Nn * Nn;
        #pragma unroll
        for (int r = 0; r < 10; ++r) {
            int row = min(max(i0 - 1 + r, 0), Nn - 1);
            tile[r * Nn + j] = img[row * Nn + j];
        }
        __syncthreads();
        #pragma unroll
        for (int k = 0; k < SEG; ++k) {
            int x0 = x0s[k], y0 = y0s[k];
            float wx1 = wxs[k], wy1 = wys[k];
            float wx0 = 1.0f - wx1, wy0 = 1.0f - wy1;
            bool vx0 = x0 >= 0, vx1 = x0 < Nn - 1;
            bool vy0 = y0 >= 0, vy1 = y0 < Nn - 1;
            int x0c = max(x0, 0), x1c = min(x0 + 1, Nn - 1);
            int ly0 = max(y0, 0) - i0 + 1;
            int ly1 = min(y0 + 1, Nn - 1) - i0 + 1;
            float w00 = (vx0 && vy0) ? wx0 * wy0 : 0.0f;
            float w10 = (vx1 && vy0) ? wx1 * wy0 : 0.0f;
            float w01 = (vx0 && vy1) ? wx0 * wy1 : 0.0f;
            float w11 = (vx1 && vy1) ? wx1 * wy1 : 0.0f;
            float v = w00 * tile[ly0 * Nn + x0c] + w10 * tile[ly0 * Nn + x1c]
                    + w01 * tile[ly1 * Nn + x0c] + w11 * tile[ly1 * Nn + x1c];
            __builtin_nontemporal_store(v, &outp[(((size_t)b * 3 + c) * Nn + (i0 + k)) * Nn + j]);
        }
    }
}

}  // namespace

extern "C" void kernel_launch(void* const* d_in, const int* in_sizes, int n_in,
                              void* d_out, int out_size, void* d_ws, size_t ws_size,
                              hipStream_t stream) {
    const float* image = (const float*)d_in[0];   // (B,3,N,N) f32
    const float* prim  = (const float*)d_in[1];   // (B,2,N,N) f32
    float* outp = (float*)d_out;                  // (B,3,N,N) f32

    float* gx_buf   = (float*)d_ws;                          // B*N*N floats (16MB)
    float* accu_buf = gx_buf + (size_t)Bn * Nn * Nn;         // B*N*N floats (16MB)
    float* partial  = accu_buf + (size_t)Bn * Nn * Nn;       // B*NSEG*N floats (2MB)

    kA_kernel<<<NSEG * Bn, 256, 0, stream>>>(prim, gx_buf, accu_buf, partial);
    k3_kernel<<<NSEG * Bn, 256, 0, stream>>>(accu_buf, partial, gx_buf, image, outp);
}